// Round 5
// baseline (5917.373 us; speedup 1.0000x reference)
//
#include <hip/hip_runtime.h>
#include <hip/hip_bf16.h>

#define NAT 50000
#define NBND 100000
#define MAXNB 6
#define AF 133
#define BF 147
#define HID 512
#define NMOL 128

// padded concat geometry
#define KCAT 664   // [0,147) f_bonds | [147,152) zero | [152,664) message
#define MOFF1 152
#define KWO 648    // [0,133) f_atoms | [133,136) zero | [136,648) amsg
#define MOFF2 136

typedef __attribute__((ext_vector_type(8))) unsigned short us8;
typedef __attribute__((ext_vector_type(4))) unsigned short us4;

__device__ __forceinline__ float4 relu4(float4 v) {
    return make_float4(fmaxf(v.x, 0.f), fmaxf(v.y, 0.f), fmaxf(v.z, 0.f), fmaxf(v.w, 0.f));
}
__device__ __forceinline__ unsigned short f2bf(float f) {
    unsigned int x = __float_as_uint(f);
    unsigned int r = x + 0x7fffu + ((x >> 16) & 1u);
    return (unsigned short)(r >> 16);
}
__device__ __forceinline__ float bf2f(unsigned short u) {
    return __uint_as_float(((unsigned int)u) << 16);
}

__device__ __forceinline__ void load8f(const float* p, float v[8]) {
    float4 a = ((const float4*)p)[0], b = ((const float4*)p)[1];
    v[0]=a.x; v[1]=a.y; v[2]=a.z; v[3]=a.w; v[4]=b.x; v[5]=b.y; v[6]=b.z; v[7]=b.w;
}
__device__ __forceinline__ void load8f(const __hip_bfloat16* p, float v[8]) {
    us8 u = *(const us8*)p;
#pragma unroll
    for (int j = 0; j < 8; j++) v[j] = bf2f(u[j]);
}
__device__ __forceinline__ void store8(float* p, const float v[8]) {
    ((float4*)p)[0] = make_float4(v[0],v[1],v[2],v[3]);
    ((float4*)p)[1] = make_float4(v[4],v[5],v[6],v[7]);
}
__device__ __forceinline__ void store8(__hip_bfloat16* p, const float v[8]) {
    us8 u;
#pragma unroll
    for (int j = 0; j < 8; j++) u[j] = f2bf(v[j]);
    *(us8*)p = u;
}
__device__ __forceinline__ void store4(float* p, float4 v) { *(float4*)p = v; }
__device__ __forceinline__ void store4(__hip_bfloat16* p, float4 v) {
    us4 u; u[0]=f2bf(v.x); u[1]=f2bf(v.y); u[2]=f2bf(v.z); u[3]=f2bf(v.w);
    *(us4*)p = u;
}

// catT[k][n], k in [0,KCAT): Wi^T rows 0..146, zeros 147..151, Wh^T rows 152..663
__global__ void prep_cat_k(const float* __restrict__ Wi, const float* __restrict__ Wh,
                           float* __restrict__ catT) {
    int idx = blockIdx.x * 256 + threadIdx.x;
    if (idx >= KCAT * HID) return;
    int k = idx >> 9, n = idx & 511;
    float v = 0.f;
    if (k < BF) v = Wi[n * BF + k];
    else if (k >= MOFF1) v = Wh[n * HID + (k - MOFF1)];
    catT[idx] = v;
}
// woT[k][n], k in [0,KWO): Wo cols 0..132, zeros 133..135, Wo cols 133..644
__global__ void prep_wo_k(const float* __restrict__ Wo, float* __restrict__ woT) {
    int idx = blockIdx.x * 256 + threadIdx.x;
    if (idx >= KWO * HID) return;
    int k = idx >> 9, n = idx & 511;
    float v = 0.f;
    if (k < AF) v = Wo[n * (AF + HID) + k];
    else if (k >= MOFF2) v = Wo[n * (AF + HID) + (k - 3)];
    woT[idx] = v;
}

// Fused fp32 GEMM, N=512 fixed, 128x128 tiles, 8x8 per thread.
// MODE 0: out = relu(f_bonds @ Wi^T)                                          K=147
// MODE 1: out = relu(concat(f_bonds[i], amsg[idx1[i]]-cur[idx2[i]]) @ catT)   K=KCAT
// MODE 2: outF = relu(concat(f_atoms[a], amsg[a]) @ woT + bias)               K=KWO
template<int MODE, typename T>
__global__ __launch_bounds__(256) void gemm_k(
    const float* __restrict__ Afeat,
    const T* __restrict__ Amsg,
    const T* __restrict__ Aprev,
    const int* __restrict__ idx1,
    const int* __restrict__ idx2,
    const float* __restrict__ BT,
    const float* __restrict__ bias,
    T* __restrict__ outT,
    float* __restrict__ outF,
    int M, int K)
{
    __shared__ float As[16][132];   // +4 pad: bank-phase shift per row
    __shared__ float Bs[16][132];

    // bijective chunked XCD swizzle: co-locate the 4 column-blocks of a row-panel
    int nwg = gridDim.x;
    int q = nwg >> 3, r = nwg & 7;
    int xcd = blockIdx.x & 7, pos = blockIdx.x >> 3;
    int newid = (xcd < r ? xcd * (q + 1) : r * (q + 1) + (xcd - r) * q) + pos;
    const int m0 = (newid >> 2) * 128;
    const int n0 = (newid & 3) * 128;

    const int tid = threadIdx.x;
    const int tx = tid & 15;
    const int ty = tid >> 4;

    const int ar  = tid >> 1;
    const int ac0 = (tid & 1) * 8;
    const int br  = tid >> 4;
    const int bc0 = (tid & 15) * 8;

    int ia1 = 0, ia2 = 0;
    if (MODE == 1) {
        int grow = m0 + ar;
        if (grow < M) { ia1 = idx1[grow]; ia2 = idx2[grow]; }
    }

    float acc[8][8];
#pragma unroll
    for (int i = 0; i < 8; i++)
#pragma unroll
        for (int j = 0; j < 8; j++) acc[i][j] = 0.f;

    for (int k0 = 0; k0 < K; k0 += 16) {
        // ---- A tile (store transposed: As[k][m]) ----
        {
            const int grow = m0 + ar;
            const int c0 = k0 + ac0;
            float v[8];
#pragma unroll
            for (int j = 0; j < 8; j++) v[j] = 0.f;
            if (grow < M) {
                if (MODE == 0) {
#pragma unroll
                    for (int j = 0; j < 8; j++) {
                        int k = c0 + j;
                        if (k < BF) v[j] = Afeat[(size_t)grow * BF + k];
                    }
                } else if (MODE == 1) {
                    if (c0 >= MOFF1 && c0 + 8 <= KCAT) {
                        float x[8], y[8];
                        load8f(Amsg  + (size_t)ia1 * HID + (c0 - MOFF1), x);
                        load8f(Aprev + (size_t)ia2 * HID + (c0 - MOFF1), y);
#pragma unroll
                        for (int j = 0; j < 8; j++) v[j] = x[j] - y[j];
                    } else if (c0 < MOFF1) {
#pragma unroll
                        for (int j = 0; j < 8; j++) {
                            int k = c0 + j;
                            if (k < BF) v[j] = Afeat[(size_t)grow * BF + k];
                        }
                    }
                } else { // MODE 2
                    if (c0 >= MOFF2 && c0 + 8 <= KWO) {
                        load8f(Amsg + (size_t)grow * HID + (c0 - MOFF2), v);
                    } else if (c0 < MOFF2) {
#pragma unroll
                        for (int j = 0; j < 8; j++) {
                            int k = c0 + j;
                            if (k < AF) v[j] = Afeat[(size_t)grow * AF + k];
                        }
                    }
                }
            }
#pragma unroll
            for (int j = 0; j < 8; j++) As[ac0 + j][ar] = v[j];
        }
        // ---- B tile ----
        {
            int k = k0 + br;
            float4 v0 = make_float4(0.f,0.f,0.f,0.f), v1 = v0;
            if (k < K) {
                const float4* p = (const float4*)(BT + (size_t)k * HID + n0 + bc0);
                v0 = p[0]; v1 = p[1];
            }
            *(float4*)&Bs[br][bc0]     = v0;
            *(float4*)&Bs[br][bc0 + 4] = v1;
        }
        __syncthreads();

#pragma unroll
        for (int k = 0; k < 16; k++) {
            float4 a0 = *(const float4*)&As[k][ty * 8];
            float4 a1 = *(const float4*)&As[k][ty * 8 + 4];
            float4 b0 = *(const float4*)&Bs[k][tx * 4];
            float4 b1 = *(const float4*)&Bs[k][tx * 4 + 64];
            float a[8] = {a0.x,a0.y,a0.z,a0.w,a1.x,a1.y,a1.z,a1.w};
            float b[8] = {b0.x,b0.y,b0.z,b0.w,b1.x,b1.y,b1.z,b1.w};
#pragma unroll
            for (int i = 0; i < 8; i++)
#pragma unroll
                for (int j = 0; j < 8; j++)
                    acc[i][j] += a[i] * b[j];
        }
        __syncthreads();
    }

    // ---- epilogue ----
#pragma unroll
    for (int i = 0; i < 8; i++) {
        int row = m0 + ty * 8 + i;
        if (row >= M) continue;
        size_t rb = (size_t)row * HID;
#pragma unroll
        for (int g = 0; g < 2; g++) {
            int col = n0 + g * 64 + tx * 4;
            float4 v = make_float4(acc[i][g*4+0], acc[i][g*4+1], acc[i][g*4+2], acc[i][g*4+3]);
            if (MODE == 2) {
                float4 bb = *(const float4*)(bias + col);
                v.x += bb.x; v.y += bb.y; v.z += bb.z; v.w += bb.w;
                store4(outF + rb + col, relu4(v));
            } else {
                store4(outT + rb + col, relu4(v));
            }
        }
    }
}

// amsg[a][:] = sum_nb msg[a2b[a][nb]][:]
template<typename T>
__global__ void gather_sum_k(const T* __restrict__ msg, const int* __restrict__ a2b,
                             T* __restrict__ amsg) {
    int t = blockIdx.x * 256 + threadIdx.x;   // NAT * 64 threads
    if (t >= NAT * 64) return;
    int a = t >> 6, c8 = (t & 63) * 8;
    float s[8];
#pragma unroll
    for (int j = 0; j < 8; j++) s[j] = 0.f;
#pragma unroll
    for (int nb = 0; nb < MAXNB; nb++) {
        int b = a2b[a * MAXNB + nb];
        float v[8];
        load8f(msg + (size_t)b * HID + c8, v);
#pragma unroll
        for (int j = 0; j < 8; j++) s[j] += v[j];
    }
    store8(amsg + (size_t)a * HID + c8, s);
}

// per-molecule mean pool; mol_ids sorted ascending; ah fp32
__global__ void pool_k(const float* __restrict__ ah, const int* __restrict__ mol_ids,
                       float* __restrict__ out) {
    int m = blockIdx.x;
    int c = blockIdx.y * 256 + threadIdx.x;
    int lo = 0, hi = NAT;
    while (lo < hi) { int mid = (lo + hi) >> 1; if (mol_ids[mid] < m) lo = mid + 1; else hi = mid; }
    int start = lo;
    hi = NAT;
    while (lo < hi) { int mid = (lo + hi) >> 1; if (mol_ids[mid] < m + 1) lo = mid + 1; else hi = mid; }
    int end = lo;
    float s = 0.f;
    for (int a = start; a < end; a++) s += ah[(size_t)a * HID + c];
    float cnt = (float)(end - start);
    out[(size_t)m * HID + c] = s / fmaxf(cnt, 1.f);
}

template<typename T>
static void run_all(const float* f_atoms, const float* f_bonds,
                    const float* ano_f_atoms, const float* ano_f_bonds,
                    const float* Wi, const float* Wh, const float* Wo, const float* bo,
                    const int* a2b, const int* b2a, const int* b2revb, const int* mol_ids,
                    const int* ano_a2b, const int* ano_b2a, const int* ano_b2revb,
                    const int* ano_mol_ids, float* out, void* d_ws, hipStream_t stream) {
    char* ws = (char*)d_ws;
    T* cur = (T*)ws;            ws += (size_t)NBND * HID * sizeof(T);
    char* nxt_raw = ws;
    T* nxt = (T*)ws;            ws += (size_t)NBND * HID * sizeof(T);
    T* amsg = (T*)ws;           ws += (size_t)NAT * HID * sizeof(T);
    float* catT = (float*)ws;   ws += (size_t)KCAT * HID * sizeof(float);
    float* woT = (float*)ws;

    prep_cat_k<<<(KCAT * HID + 255) / 256, 256, 0, stream>>>(Wi, Wh, catT);
    prep_wo_k<<<(KWO * HID + 255) / 256, 256, 0, stream>>>(Wo, woT);

    const int nwgB = 4 * ((NBND + 127) / 128);
    const int nwgA = 4 * ((NAT + 127) / 128);
    const int gsBlocks = (NAT * 64 + 255) / 256;

    for (int e = 0; e < 2; e++) {
        const float* fa = e ? ano_f_atoms : f_atoms;
        const float* fb = e ? ano_f_bonds : f_bonds;
        const int* e_a2b = e ? ano_a2b : a2b;
        const int* e_b2a = e ? ano_b2a : b2a;
        const int* e_b2revb = e ? ano_b2revb : b2revb;
        const int* e_mids = e ? ano_mol_ids : mol_ids;

        T* c = cur; T* n = nxt;
        gemm_k<0, T><<<nwgB, 256, 0, stream>>>(fb, (const T*)nullptr, (const T*)nullptr,
                                               nullptr, nullptr, catT, nullptr,
                                               c, nullptr, NBND, BF);
        for (int d = 0; d < 2; d++) {
            gather_sum_k<T><<<gsBlocks, 256, 0, stream>>>(c, e_a2b, amsg);
            gemm_k<1, T><<<nwgB, 256, 0, stream>>>(fb, amsg, c, e_b2a, e_b2revb, catT,
                                                   nullptr, n, nullptr, NBND, KCAT);
            T* t = c; c = n; n = t;
        }
        gather_sum_k<T><<<gsBlocks, 256, 0, stream>>>(c, e_a2b, amsg);
        float* ah = (float*)nxt_raw;   // after 2 swaps, nxt region content is dead
        gemm_k<2, T><<<nwgA, 256, 0, stream>>>(fa, amsg, (const T*)nullptr,
                                               nullptr, nullptr, woT, bo,
                                               (T*)nullptr, ah, NAT, KWO);
        pool_k<<<dim3(NMOL, 2), 256, 0, stream>>>(ah, e_mids, out + (size_t)e * NMOL * HID);
    }
}

extern "C" void kernel_launch(void* const* d_in, const int* in_sizes, int n_in,
                              void* d_out, int out_size, void* d_ws, size_t ws_size,
                              hipStream_t stream) {
    const float* f_atoms     = (const float*)d_in[0];
    const float* f_bonds     = (const float*)d_in[1];
    const float* ano_f_atoms = (const float*)d_in[2];
    const float* ano_f_bonds = (const float*)d_in[3];
    const float* Wi = (const float*)d_in[4];
    const float* Wh = (const float*)d_in[5];
    const float* Wo = (const float*)d_in[6];
    const float* bo = (const float*)d_in[7];
    const int* a2b     = (const int*)d_in[8];
    const int* b2a     = (const int*)d_in[9];
    const int* b2revb  = (const int*)d_in[10];
    const int* mol_ids = (const int*)d_in[11];
    const int* ano_a2b     = (const int*)d_in[12];
    const int* ano_b2a     = (const int*)d_in[13];
    const int* ano_b2revb  = (const int*)d_in[14];
    const int* ano_mol_ids = (const int*)d_in[15];
    float* out = (float*)d_out;

    const size_t wfix = ((size_t)KCAT + KWO) * HID * sizeof(float);
    const size_t need_f = ((size_t)2 * NBND + NAT) * HID * sizeof(float) + wfix;
    const size_t need_h = ((size_t)2 * NBND + NAT) * HID * sizeof(__hip_bfloat16) + wfix;

    if (ws_size >= need_f) {
        run_all<float>(f_atoms, f_bonds, ano_f_atoms, ano_f_bonds, Wi, Wh, Wo, bo,
                       a2b, b2a, b2revb, mol_ids, ano_a2b, ano_b2a, ano_b2revb,
                       ano_mol_ids, out, d_ws, stream);
    } else if (ws_size >= need_h) {
        run_all<__hip_bfloat16>(f_atoms, f_bonds, ano_f_atoms, ano_f_bonds, Wi, Wh, Wo, bo,
                                a2b, b2a, b2revb, mol_ids, ano_a2b, ano_b2a, ano_b2revb,
                                ano_mol_ids, out, d_ws, stream);
    }
    // else: insufficient workspace — no safe path; do nothing (will fail validation
    // visibly rather than fault).
}

// Round 8
// 2682.972 us; speedup vs baseline: 2.2055x; 2.2055x over previous
//
#include <hip/hip_runtime.h>

#define NAT 50000
#define NBND 100000
#define MAXNB 6
#define AF 133
#define BF 147
#define HID 512
#define NMOL 128
#define KP 672          // padded K for both concat-GEMMs (multiple of 32)

typedef __attribute__((ext_vector_type(8))) unsigned short us8;
typedef __attribute__((ext_vector_type(8))) short bfrag;    // 8 bf16 (4 VGPRs)
typedef __attribute__((ext_vector_type(4))) float f4;

__device__ __forceinline__ unsigned short f2bf(float f) {
    unsigned int x = __float_as_uint(f);
    unsigned int r = x + 0x7fffu + ((x >> 16) & 1u);
    return (unsigned short)(r >> 16);
}
__device__ __forceinline__ float bf2f(unsigned short u) {
    return __uint_as_float(((unsigned int)u) << 16);
}

// catW[n][k] bf16: k<147: Wi[n][k] | 147..151: 0 | 152..663: Wh[n][k-152] | >=664: 0
__global__ void prep_catW(const float* __restrict__ Wi, const float* __restrict__ Wh,
                          unsigned short* __restrict__ catW) {
    int idx = blockIdx.x * 256 + threadIdx.x;
    if (idx >= HID * KP) return;
    int n = idx / KP, k = idx - n * KP;
    float v = 0.f;
    if (k < BF) v = Wi[n * BF + k];
    else if (k >= 152 && k < 664) v = Wh[n * HID + (k - 152)];
    catW[idx] = f2bf(v);
}
// woW[n][k] bf16: k<133: Wo[n][k] | 133..135: 0 | 136..647: Wo[n][k-3] | >=648: 0
__global__ void prep_woW(const float* __restrict__ Wo, unsigned short* __restrict__ woW) {
    int idx = blockIdx.x * 256 + threadIdx.x;
    if (idx >= HID * KP) return;
    int n = idx / KP, k = idx - n * KP;
    float v = 0.f;
    if (k < AF) v = Wo[n * (AF + HID) + k];
    else if (k >= 136 && k < 648) v = Wo[n * (AF + HID) + (k - 3)];
    woW[idx] = f2bf(v);
}

// MFMA bf16 GEMM, out[M,512] = epi(Acat @ W^T), 128x128 tile, 4 waves, K-step 32.
// A row i: [0,FEAT): Afeat | [FEAT,MOFF): 0 | [MOFF,KEND): Adm[i] | [KEND,KP): 0
// MODE 0: Wi GEMM (feature-only, 5 K-steps), out bf16 relu
// MODE 1: concat(f_bonds, dm) GEMM,           out bf16 relu
// MODE 2: concat(f_atoms, amsg) GEMM + bias,  out fp32 relu
template<int MODE>
__global__ __launch_bounds__(256) void gemm_mfma(
    const float* __restrict__ Afeat,
    const unsigned short* __restrict__ Adm,
    const unsigned short* __restrict__ BW,
    const float* __restrict__ bias,
    unsigned short* __restrict__ outB,
    float* __restrict__ outF,
    int M)
{
    constexpr int FEAT = (MODE == 2) ? AF : BF;
    constexpr int MOFF = (MODE == 0) ? 160 : (MODE == 1) ? 152 : 136;
    constexpr int KEND = (MODE == 0) ? 160 : (MODE == 1) ? 664 : 648;
    constexpr int NK   = (MODE == 0) ? 5 : 21;

    __shared__ unsigned short As[128][40];   // 32 k + 8 pad: 2-way-max bank conflicts
    __shared__ unsigned short Bs[128][40];

    // bijective chunked XCD swizzle
    int nwg = gridDim.x;
    int q = nwg >> 3, r = nwg & 7;
    int xcd = blockIdx.x & 7, pos = blockIdx.x >> 3;
    int newid = (xcd < r ? xcd * (q + 1) : r * (q + 1) + (xcd - r) * q) + pos;
    const int m0 = (newid >> 2) * 128;
    const int n0 = (newid & 3) * 128;

    const int tid  = threadIdx.x;
    const int lane = tid & 63;
    const int wid  = tid >> 6;       // 4 waves, 2x2 -> 64x64 each
    const int wm   = wid >> 1;
    const int wn   = wid & 1;
    const int l15  = lane & 15;
    const int lg   = lane >> 4;

    const int ar = tid >> 1;          // staging row (A and B)
    const int kh = (tid & 1) << 4;    // staging k-half (0 or 16)
    const int grow = m0 + ar;

    const f4 fzero = {0.f, 0.f, 0.f, 0.f};
    f4 acc[4][4];
#pragma unroll
    for (int i = 0; i < 4; i++)
#pragma unroll
        for (int j = 0; j < 4; j++) acc[i][j] = fzero;

    for (int ks = 0; ks < NK; ks++) {
        const int k0 = ks * 32;
        const int c0 = k0 + kh;
        // ---- A tile ----
        us8 h0 = {0, 0, 0, 0, 0, 0, 0, 0};
        us8 h1 = {0, 0, 0, 0, 0, 0, 0, 0};
        if (grow < M) {
            if (c0 >= MOFF && c0 + 16 <= KEND) {          // pure message region
                const us8* p = (const us8*)(Adm + (size_t)grow * HID + (c0 - MOFF));
                h0 = p[0]; h1 = p[1];
            } else {
                unsigned short t[16];
#pragma unroll
                for (int j = 0; j < 16; j++) {
                    int c = c0 + j;
                    unsigned short v = 0;
                    if (c < FEAT) v = f2bf(Afeat[(size_t)grow * FEAT + c]);
                    else if (c >= MOFF && c < KEND) v = Adm[(size_t)grow * HID + (c - MOFF)];
                    t[j] = v;
                }
#pragma unroll
                for (int j = 0; j < 8; j++) { h0[j] = t[j]; h1[j] = t[j + 8]; }
            }
        }
        *(us8*)&As[ar][kh]     = h0;
        *(us8*)&As[ar][kh + 8] = h1;
        // ---- B tile (BW is [512][KP] bf16, native W[n][k] layout) ----
        {
            const us8* p = (const us8*)(BW + (size_t)(n0 + ar) * KP + c0);
            *(us8*)&Bs[ar][kh]     = p[0];
            *(us8*)&Bs[ar][kh + 8] = p[1];
        }
        __syncthreads();

        bfrag a[4], b[4];
#pragma unroll
        for (int mf = 0; mf < 4; mf++)
            a[mf] = *(const bfrag*)&As[wm * 64 + mf * 16 + l15][lg * 8];
#pragma unroll
        for (int nf = 0; nf < 4; nf++)
            b[nf] = *(const bfrag*)&Bs[wn * 64 + nf * 16 + l15][lg * 8];
#pragma unroll
        for (int mf = 0; mf < 4; mf++)
#pragma unroll
            for (int nf = 0; nf < 4; nf++)
                acc[mf][nf] = __builtin_amdgcn_mfma_f32_16x16x32_bf16(
                    a[mf], b[nf], acc[mf][nf], 0, 0, 0);
        __syncthreads();
    }

    // ---- epilogue: C/D layout col = lane&15, row = (lane>>4)*4 + reg ----
#pragma unroll
    for (int mf = 0; mf < 4; mf++) {
#pragma unroll
        for (int rg = 0; rg < 4; rg++) {
            int R = m0 + wm * 64 + mf * 16 + lg * 4 + rg;
            if (R >= M) continue;
#pragma unroll
            for (int nf = 0; nf < 4; nf++) {
                int C = n0 + wn * 64 + nf * 16 + l15;
                float v = acc[mf][nf][rg];
                if (MODE == 2) {
                    v += bias[C];
                    outF[(size_t)R * HID + C] = fmaxf(v, 0.f);
                } else {
                    outB[(size_t)R * HID + C] = f2bf(fmaxf(v, 0.f));
                }
            }
        }
    }
}

// dm[b][:] = amsg[b2a[b]][:] - msg[b2revb[b]][:]   (bf16 in/out, fp32 subtract)
__global__ void dm_k(const unsigned short* __restrict__ amsg,
                     const unsigned short* __restrict__ msg,
                     const int* __restrict__ b2a, const int* __restrict__ b2revb,
                     unsigned short* __restrict__ dm) {
    int t = blockIdx.x * 256 + threadIdx.x;   // NBND*64
    if (t >= NBND * 64) return;
    int b = t >> 6, c8 = (t & 63) * 8;
    int ia = b2a[b], ir = b2revb[b];
    us8 x = *(const us8*)(amsg + (size_t)ia * HID + c8);
    us8 y = *(const us8*)(msg + (size_t)ir * HID + c8);
    us8 o;
#pragma unroll
    for (int j = 0; j < 8; j++) o[j] = f2bf(bf2f(x[j]) - bf2f(y[j]));
    *(us8*)(dm + (size_t)b * HID + c8) = o;
}

// amsg[a][:] = sum_nb msg[a2b[a][nb]][:]  (bf16 in/out, fp32 accumulate)
__global__ void gather_sum_k(const unsigned short* __restrict__ msg,
                             const int* __restrict__ a2b,
                             unsigned short* __restrict__ amsg) {
    int t = blockIdx.x * 256 + threadIdx.x;   // NAT*64
    if (t >= NAT * 64) return;
    int a = t >> 6, c8 = (t & 63) * 8;
    float s[8];
#pragma unroll
    for (int j = 0; j < 8; j++) s[j] = 0.f;
#pragma unroll
    for (int nb = 0; nb < MAXNB; nb++) {
        int b = a2b[a * MAXNB + nb];
        us8 v = *(const us8*)(msg + (size_t)b * HID + c8);
#pragma unroll
        for (int j = 0; j < 8; j++) s[j] += bf2f(v[j]);
    }
    us8 o;
#pragma unroll
    for (int j = 0; j < 8; j++) o[j] = f2bf(s[j]);
    *(us8*)(amsg + (size_t)a * HID + c8) = o;
}

// per-molecule mean pool; mol_ids sorted ascending; ah fp32
__global__ void pool_k(const float* __restrict__ ah, const int* __restrict__ mol_ids,
                       float* __restrict__ out) {
    int m = blockIdx.x;
    int c = blockIdx.y * 256 + threadIdx.x;
    int lo = 0, hi = NAT;
    while (lo < hi) { int mid = (lo + hi) >> 1; if (mol_ids[mid] < m) lo = mid + 1; else hi = mid; }
    int start = lo;
    hi = NAT;
    while (lo < hi) { int mid = (lo + hi) >> 1; if (mol_ids[mid] < m + 1) lo = mid + 1; else hi = mid; }
    int end = lo;
    float s = 0.f;
    for (int a = start; a < end; a++) s += ah[(size_t)a * HID + c];
    float cnt = (float)(end - start);
    out[(size_t)m * HID + c] = s / fmaxf(cnt, 1.f);
}

extern "C" void kernel_launch(void* const* d_in, const int* in_sizes, int n_in,
                              void* d_out, int out_size, void* d_ws, size_t ws_size,
                              hipStream_t stream) {
    const float* f_atoms     = (const float*)d_in[0];
    const float* f_bonds     = (const float*)d_in[1];
    const float* ano_f_atoms = (const float*)d_in[2];
    const float* ano_f_bonds = (const float*)d_in[3];
    const float* Wi = (const float*)d_in[4];
    const float* Wh = (const float*)d_in[5];
    const float* Wo = (const float*)d_in[6];
    const float* bo = (const float*)d_in[7];
    const int* a2b     = (const int*)d_in[8];
    const int* b2a     = (const int*)d_in[9];
    const int* b2revb  = (const int*)d_in[10];
    const int* mol_ids = (const int*)d_in[11];
    const int* ano_a2b     = (const int*)d_in[12];
    const int* ano_b2a     = (const int*)d_in[13];
    const int* ano_b2revb  = (const int*)d_in[14];
    const int* ano_mol_ids = (const int*)d_in[15];
    float* out = (float*)d_out;

    // workspace layout (bf16 messages): 257.4 MB total
    char* ws = (char*)d_ws;
    unsigned short* msgA = (unsigned short*)ws;  ws += (size_t)NBND * HID * 2;   // 102.4 MB
    char* msgB_raw = ws;
    unsigned short* msgB = (unsigned short*)ws;  ws += (size_t)NBND * HID * 2;   // 102.4 MB
    unsigned short* amsg = (unsigned short*)ws;  ws += (size_t)NAT * HID * 2;    //  51.2 MB
    unsigned short* catW = (unsigned short*)ws;  ws += (size_t)HID * KP * 2;     //  0.69 MB
    unsigned short* woW  = (unsigned short*)ws;  ws += (size_t)HID * KP * 2;     //  0.69 MB

    const size_t need = ((size_t)2 * NBND + NAT) * HID * 2 + (size_t)2 * HID * KP * 2;
    if (ws_size < need) return;   // visible failure, no fault

    prep_catW<<<(HID * KP + 255) / 256, 256, 0, stream>>>(Wi, Wh, catW);
    prep_woW<<<(HID * KP + 255) / 256, 256, 0, stream>>>(Wo, woW);

    const int nwgB = 4 * ((NBND + 127) / 128);   // 3128
    const int nwgA = 4 * ((NAT + 127) / 128);    // 1564
    const int gsBlocks = (NAT * 64 + 255) / 256;
    const int dmBlocks = (NBND * 64 + 255) / 256;

    for (int e = 0; e < 2; e++) {
        const float* fa = e ? ano_f_atoms : f_atoms;
        const float* fb = e ? ano_f_bonds : f_bonds;
        const int* e_a2b = e ? ano_a2b : a2b;
        const int* e_b2a = e ? ano_b2a : b2a;
        const int* e_b2revb = e ? ano_b2revb : b2revb;
        const int* e_mids = e ? ano_mol_ids : mol_ids;

        // msgA = relu(f_bonds @ Wi^T)
        gemm_mfma<0><<<nwgB, 256, 0, stream>>>(fb, (const unsigned short*)nullptr, catW,
                                               nullptr, msgA, nullptr, NBND);
        for (int d = 0; d < 2; d++) {
            gather_sum_k<<<gsBlocks, 256, 0, stream>>>(msgA, e_a2b, amsg);
            dm_k<<<dmBlocks, 256, 0, stream>>>(amsg, msgA, e_b2a, e_b2revb, msgB);
            // msgA = relu(concat(f_bonds, dm) @ [Wi|Wh]^T)
            gemm_mfma<1><<<nwgB, 256, 0, stream>>>(fb, msgB, catW,
                                                   nullptr, msgA, nullptr, NBND);
        }
        gather_sum_k<<<gsBlocks, 256, 0, stream>>>(msgA, e_a2b, amsg);
        // ah(fp32, reuses msgB region) = relu(concat(f_atoms, amsg) @ Wo^T + bo)
        float* ah = (float*)msgB_raw;
        gemm_mfma<2><<<nwgA, 256, 0, stream>>>(fa, amsg, woW,
                                               bo, nullptr, ah, NAT);
        pool_k<<<dim3(NMOL, 2), 256, 0, stream>>>(ah, e_mids, out + (size_t)e * NMOL * HID);
    }
}

// Round 10
// 1970.994 us; speedup vs baseline: 3.0022x; 1.3612x over previous
//
#include <hip/hip_runtime.h>

#define NAT 50000
#define NBND 100000
#define MAXNB 6
#define AF 133
#define BF 147
#define HID 512
#define NMOL 128
#define KP 672          // padded K; message region is [160, 672) == exactly 512
#define MOFF 160

typedef __attribute__((ext_vector_type(8))) unsigned short us8;
typedef __attribute__((ext_vector_type(8))) short bfrag;    // 8 bf16 (4 VGPRs)
typedef __attribute__((ext_vector_type(4))) float f4;

__device__ __forceinline__ unsigned short f2bf(float f) {
    unsigned int x = __float_as_uint(f);
    unsigned int r = x + 0x7fffu + ((x >> 16) & 1u);
    return (unsigned short)(r >> 16);
}
__device__ __forceinline__ float bf2f(unsigned short u) {
    return __uint_as_float(((unsigned int)u) << 16);
}

// async 16B/lane global->LDS DMA; lds dest = wave-uniform base + lane*16
__device__ __forceinline__ void dma16(const void* g, void* l) {
    __builtin_amdgcn_global_load_lds(
        (__attribute__((address_space(1))) void*)(void*)g,
        (__attribute__((address_space(3))) void*)l, 16, 0, 0);
}

// catW[n][k] bf16: k<147: Wi | 147..159: 0 | 160..671: Wh[n][k-160]
__global__ void prep_catW(const float* __restrict__ Wi, const float* __restrict__ Wh,
                          unsigned short* __restrict__ catW) {
    int idx = blockIdx.x * 256 + threadIdx.x;
    if (idx >= HID * KP) return;
    int n = idx / KP, k = idx - n * KP;
    float v = 0.f;
    if (k < BF) v = Wi[n * BF + k];
    else if (k >= MOFF) v = Wh[n * HID + (k - MOFF)];
    catW[idx] = f2bf(v);
}
// woW[n][k] bf16: k<133: Wo[n][k] | 133..159: 0 | 160..671: Wo[n][k-27]
__global__ void prep_woW(const float* __restrict__ Wo, unsigned short* __restrict__ woW) {
    int idx = blockIdx.x * 256 + threadIdx.x;
    if (idx >= HID * KP) return;
    int n = idx / KP, k = idx - n * KP;
    float v = 0.f;
    if (k < AF) v = Wo[n * (AF + HID) + k];
    else if (k >= MOFF) v = Wo[n * (AF + HID) + (k - 27)];
    woW[idx] = f2bf(v);
}

// MFMA bf16 GEMM, out[M,512], 128x128 tile, 4 waves, K-step 32, 2-phase dbuf.
// LDS tiles [128][32] linear (global_load_lds-compatible) with chunk XOR swizzle
// phys = logical ^ ((row ^ row>>2)&3), applied on DMA source addr and frag read.
// MODE 0: relu(f_bonds @ Wi^T)  K-tiles 0..4 (feature-only)     -> bf16
// MODE 1: relu(concat(f_bonds, dm) @ catW^T)    tiles 0..20     -> bf16
// MODE 2: relu(concat(f_atoms, amsg) @ woW^T + bias) tiles 0..20 -> fp32
template<int MODE>
__global__ __launch_bounds__(256) void gemm_mfma(
    const float* __restrict__ Afeat,
    const unsigned short* __restrict__ Amsg,
    const unsigned short* __restrict__ BW,
    const float* __restrict__ bias,
    unsigned short* __restrict__ outB,
    float* __restrict__ outF,
    int M)
{
    constexpr int FEAT  = (MODE == 2) ? AF : BF;
    constexpr int NK    = (MODE == 0) ? 5 : 21;
    constexpr int NFEAT = 5;    // tiles < NFEAT are feature tiles (reg-staged)

    __shared__ unsigned short As[2][128 * 32];   // 8KB per buffer
    __shared__ unsigned short Bs[2][128 * 32];

    // bijective chunked XCD swizzle
    int nwg = gridDim.x;
    int q = nwg >> 3, r = nwg & 7;
    int xcd = blockIdx.x & 7, pos = blockIdx.x >> 3;
    int newid = (xcd < r ? xcd * (q + 1) : r * (q + 1) + (xcd - r) * q) + pos;
    const int m0 = (newid >> 2) * 128;
    const int n0 = (newid & 3) * 128;

    const int tid  = threadIdx.x;
    const int lane = tid & 63;
    const int wid  = tid >> 6;       // 4 waves, 2x2 -> 64x64 each
    const int wm   = wid >> 1;
    const int wn   = wid & 1;
    const int l15  = lane & 15;
    const int lg   = lane >> 4;

    const int drow = lane >> 2;      // DMA: row within 16-row group
    const int dchk = lane & 3;       // DMA: physical 16B chunk
    const int slr   = tid >> 1;      // slow path: row
    const int shalf = tid & 1;       // slow path: chunk pair

    auto stageB = [&](int ks, int buf) {
#pragma unroll
        for (int j = 0; j < 2; j++) {
            int R0 = wid * 32 + j * 16;
            int lr = R0 + drow;
            int sw = (lr ^ (lr >> 2)) & 3;
            const unsigned short* src =
                BW + (size_t)(n0 + lr) * KP + ks * 32 + ((dchk ^ sw) << 3);
            dma16(src, &Bs[buf][R0 * 32]);
        }
    };
    auto stageA_dma = [&](int ks, int buf) {
        const int kb = ks * 32 - MOFF;
#pragma unroll
        for (int j = 0; j < 2; j++) {
            int R0 = wid * 32 + j * 16;
            int lr = R0 + drow;
            int gr = m0 + lr; gr = gr < M ? gr : M - 1;   // clamp: garbage rows masked at C-write
            int sw = (lr ^ (lr >> 2)) & 3;
            const unsigned short* src =
                Amsg + (size_t)gr * HID + kb + ((dchk ^ sw) << 3);
            dma16(src, &As[buf][R0 * 32]);
        }
    };
    auto stageA_slow = [&](int ks, int buf) {
        const int k0 = ks * 32;
        const int gr = m0 + slr;
        const int sw = (slr ^ (slr >> 2)) & 3;
#pragma unroll
        for (int h = 0; h < 2; h++) {
            int c = shalf * 2 + h;
            us8 v = {0, 0, 0, 0, 0, 0, 0, 0};
            if (gr < M) {
#pragma unroll
                for (int e = 0; e < 8; e++) {
                    int k = k0 + c * 8 + e;
                    if (k < FEAT) v[e] = f2bf(Afeat[(size_t)gr * FEAT + k]);
                }
            }
            *(us8*)&As[buf][slr * 32 + ((c ^ sw) << 3)] = v;
        }
    };

    const f4 fzero = {0.f, 0.f, 0.f, 0.f};
    f4 acc[4][4];
#pragma unroll
    for (int i = 0; i < 4; i++)
#pragma unroll
        for (int j = 0; j < 4; j++) acc[i][j] = fzero;

    // prologue: tile 0 (always a feature tile)
    stageB(0, 0);
    stageA_slow(0, 0);
    __syncthreads();

    int cur = 0;
    for (int ks = 0; ks < NK; ks++) {
        const int nxt = ks + 1;
        const bool hn = nxt < NK;
        const bool fast = hn && (nxt >= NFEAT);
        if (hn) {
            stageB(nxt, cur ^ 1);                 // async DMA, overlaps compute
            if (fast) stageA_dma(nxt, cur ^ 1);
        }
        bfrag a[4], b[4];
#pragma unroll
        for (int mf = 0; mf < 4; mf++) {
            int rr = wm * 64 + mf * 16 + l15;
            int p = lg ^ ((rr ^ (rr >> 2)) & 3);
            a[mf] = *(const bfrag*)&As[cur][rr * 32 + p * 8];
        }
#pragma unroll
        for (int nf = 0; nf < 4; nf++) {
            int rr = wn * 64 + nf * 16 + l15;
            int p = lg ^ ((rr ^ (rr >> 2)) & 3);
            b[nf] = *(const bfrag*)&Bs[cur][rr * 32 + p * 8];
        }
#pragma unroll
        for (int mf = 0; mf < 4; mf++)
#pragma unroll
            for (int nf = 0; nf < 4; nf++)
                acc[mf][nf] = __builtin_amdgcn_mfma_f32_16x16x32_bf16(
                    a[mf], b[nf], acc[mf][nf], 0, 0, 0);
        __syncthreads();          // drains this step's DMA + frees buf[cur]
        if (hn && !fast) {        // feature tile: reg-staged after the barrier
            stageA_slow(nxt, cur ^ 1);
            __syncthreads();
        }
        cur ^= 1;
    }

    // epilogue: C/D layout col = lane&15, row = (lane>>4)*4 + reg  (validated r8)
#pragma unroll
    for (int mf = 0; mf < 4; mf++) {
#pragma unroll
        for (int rg = 0; rg < 4; rg++) {
            int R = m0 + wm * 64 + mf * 16 + lg * 4 + rg;
            if (R >= M) continue;
#pragma unroll
            for (int nf = 0; nf < 4; nf++) {
                int C = n0 + wn * 64 + nf * 16 + l15;
                float v = acc[mf][nf][rg];
                if (MODE == 2) {
                    v += bias[C];
                    outF[(size_t)R * HID + C] = fmaxf(v, 0.f);
                } else {
                    outB[(size_t)R * HID + C] = f2bf(fmaxf(v, 0.f));
                }
            }
        }
    }
}

// dm[b][:] = amsg[b2a[b]][:] - msg[b2revb[b]][:]   (bf16, fp32 subtract)
__global__ void dm_k(const unsigned short* __restrict__ amsg,
                     const unsigned short* __restrict__ msg,
                     const int* __restrict__ b2a, const int* __restrict__ b2revb,
                     unsigned short* __restrict__ dm) {
    int t = blockIdx.x * 256 + threadIdx.x;   // NBND*64
    if (t >= NBND * 64) return;
    int b = t >> 6, c8 = (t & 63) * 8;
    int ia = b2a[b], ir = b2revb[b];
    us8 x = *(const us8*)(amsg + (size_t)ia * HID + c8);
    us8 y = *(const us8*)(msg + (size_t)ir * HID + c8);
    us8 o;
#pragma unroll
    for (int j = 0; j < 8; j++) o[j] = f2bf(bf2f(x[j]) - bf2f(y[j]));
    *(us8*)(dm + (size_t)b * HID + c8) = o;
}

// amsg[a][:] = sum_nb msg[a2b[a][nb]][:]  (bf16, fp32 accumulate)
__global__ void gather_sum_k(const unsigned short* __restrict__ msg,
                             const int* __restrict__ a2b,
                             unsigned short* __restrict__ amsg) {
    int t = blockIdx.x * 256 + threadIdx.x;   // NAT*64
    if (t >= NAT * 64) return;
    int a = t >> 6, c8 = (t & 63) * 8;
    float s[8];
#pragma unroll
    for (int j = 0; j < 8; j++) s[j] = 0.f;
#pragma unroll
    for (int nb = 0; nb < MAXNB; nb++) {
        int b = a2b[a * MAXNB + nb];
        us8 v = *(const us8*)(msg + (size_t)b * HID + c8);
#pragma unroll
        for (int j = 0; j < 8; j++) s[j] += bf2f(v[j]);
    }
    us8 o;
#pragma unroll
    for (int j = 0; j < 8; j++) o[j] = f2bf(s[j]);
    *(us8*)(amsg + (size_t)a * HID + c8) = o;
}

// per-molecule mean pool; mol_ids sorted ascending; ah fp32
__global__ void pool_k(const float* __restrict__ ah, const int* __restrict__ mol_ids,
                       float* __restrict__ out) {
    int m = blockIdx.x;
    int c = blockIdx.y * 256 + threadIdx.x;
    int lo = 0, hi = NAT;
    while (lo < hi) { int mid = (lo + hi) >> 1; if (mol_ids[mid] < m) lo = mid + 1; else hi = mid; }
    int start = lo;
    hi = NAT;
    while (lo < hi) { int mid = (lo + hi) >> 1; if (mol_ids[mid] < m + 1) lo = mid + 1; else hi = mid; }
    int end = lo;
    float s = 0.f;
    for (int a = start; a < end; a++) s += ah[(size_t)a * HID + c];
    float cnt = (float)(end - start);
    out[(size_t)m * HID + c] = s / fmaxf(cnt, 1.f);
}

extern "C" void kernel_launch(void* const* d_in, const int* in_sizes, int n_in,
                              void* d_out, int out_size, void* d_ws, size_t ws_size,
                              hipStream_t stream) {
    const float* f_atoms     = (const float*)d_in[0];
    const float* f_bonds     = (const float*)d_in[1];
    const float* ano_f_atoms = (const float*)d_in[2];
    const float* ano_f_bonds = (const float*)d_in[3];
    const float* Wi = (const float*)d_in[4];
    const float* Wh = (const float*)d_in[5];
    const float* Wo = (const float*)d_in[6];
    const float* bo = (const float*)d_in[7];
    const int* a2b     = (const int*)d_in[8];
    const int* b2a     = (const int*)d_in[9];
    const int* b2revb  = (const int*)d_in[10];
    const int* mol_ids = (const int*)d_in[11];
    const int* ano_a2b     = (const int*)d_in[12];
    const int* ano_b2a     = (const int*)d_in[13];
    const int* ano_b2revb  = (const int*)d_in[14];
    const int* ano_mol_ids = (const int*)d_in[15];
    float* out = (float*)d_out;

    // workspace layout (bf16 messages): 257.4 MB total
    char* ws = (char*)d_ws;
    unsigned short* msgA = (unsigned short*)ws;  ws += (size_t)NBND * HID * 2;
    char* msgB_raw = ws;
    unsigned short* msgB = (unsigned short*)ws;  ws += (size_t)NBND * HID * 2;
    unsigned short* amsg = (unsigned short*)ws;  ws += (size_t)NAT * HID * 2;
    unsigned short* catW = (unsigned short*)ws;  ws += (size_t)HID * KP * 2;
    unsigned short* woW  = (unsigned short*)ws;  ws += (size_t)HID * KP * 2;

    const size_t need = ((size_t)2 * NBND + NAT) * HID * 2 + (size_t)2 * HID * KP * 2;
    if (ws_size < need) return;   // visible failure, no fault

    prep_catW<<<(HID * KP + 255) / 256, 256, 0, stream>>>(Wi, Wh, catW);
    prep_woW<<<(HID * KP + 255) / 256, 256, 0, stream>>>(Wo, woW);

    const int nwgB = 4 * ((NBND + 127) / 128);   // 3128
    const int nwgA = 4 * ((NAT + 127) / 128);    // 1564
    const int gsBlocks = (NAT * 64 + 255) / 256;
    const int dmBlocks = (NBND * 64 + 255) / 256;

    for (int e = 0; e < 2; e++) {
        const float* fa = e ? ano_f_atoms : f_atoms;
        const float* fb = e ? ano_f_bonds : f_bonds;
        const int* e_a2b = e ? ano_a2b : a2b;
        const int* e_b2a = e ? ano_b2a : b2a;
        const int* e_b2revb = e ? ano_b2revb : b2revb;
        const int* e_mids = e ? ano_mol_ids : mol_ids;

        // msgA = relu(f_bonds @ Wi^T)
        gemm_mfma<0><<<nwgB, 256, 0, stream>>>(fb, (const unsigned short*)nullptr, catW,
                                               nullptr, msgA, nullptr, NBND);
        for (int d = 0; d < 2; d++) {
            gather_sum_k<<<gsBlocks, 256, 0, stream>>>(msgA, e_a2b, amsg);
            dm_k<<<dmBlocks, 256, 0, stream>>>(amsg, msgA, e_b2a, e_b2revb, msgB);
            // msgA = relu(concat(f_bonds, dm) @ [Wi|0|Wh]^T)
            gemm_mfma<1><<<nwgB, 256, 0, stream>>>(fb, msgB, catW,
                                                   nullptr, msgA, nullptr, NBND);
        }
        gather_sum_k<<<gsBlocks, 256, 0, stream>>>(msgA, e_a2b, amsg);
        // ah(fp32, reuses msgB region) = relu(concat(f_atoms, amsg) @ Wo^T + bo)
        float* ah = (float*)msgB_raw;
        gemm_mfma<2><<<nwgA, 256, 0, stream>>>(fa, amsg, woW,
                                               bo, nullptr, ah, NAT);
        pool_k<<<dim3(NMOL, 2), 256, 0, stream>>>(ah, e_mids, out + (size_t)e * NMOL * HID);
    }
}

// Round 12
// 1882.705 us; speedup vs baseline: 3.1430x; 1.0469x over previous
//
#include <hip/hip_runtime.h>

#define NAT 50000
#define NBND 100000
#define MAXNB 6
#define AF 133
#define BF 147
#define HID 512
#define NMOL 128
#define KP 672          // padded K; message region is [160, 672) == exactly 512
#define MOFF 160

typedef __attribute__((ext_vector_type(8))) unsigned short us8;
typedef __attribute__((ext_vector_type(8))) short bfrag;    // 8 bf16 (4 VGPRs)
typedef __attribute__((ext_vector_type(4))) float f4;

__device__ __forceinline__ unsigned short f2bf(float f) {
    unsigned int x = __float_as_uint(f);
    unsigned int r = x + 0x7fffu + ((x >> 16) & 1u);
    return (unsigned short)(r >> 16);
}
__device__ __forceinline__ float bf2f(unsigned short u) {
    return __uint_as_float(((unsigned int)u) << 16);
}

// async 16B/lane global->LDS DMA; lds dest = wave-uniform base + lane*16
__device__ __forceinline__ void dma16(const void* g, void* l) {
    __builtin_amdgcn_global_load_lds(
        (__attribute__((address_space(1))) void*)(void*)g,
        (__attribute__((address_space(3))) void*)l, 16, 0, 0);
}

#define WAITVM(N) asm volatile("s_waitcnt vmcnt(" #N ")" ::: "memory")

// catW[n][k] bf16: k<147: Wi | 147..159: 0 | 160..671: Wh[n][k-160]
__global__ void prep_catW(const float* __restrict__ Wi, const float* __restrict__ Wh,
                          unsigned short* __restrict__ catW) {
    int idx = blockIdx.x * 256 + threadIdx.x;
    if (idx >= HID * KP) return;
    int n = idx / KP, k = idx - n * KP;
    float v = 0.f;
    if (k < BF) v = Wi[n * BF + k];
    else if (k >= MOFF) v = Wh[n * HID + (k - MOFF)];
    catW[idx] = f2bf(v);
}
// woW[n][k] bf16: k<133: Wo[n][k] | 133..159: 0 | 160..671: Wo[n][k-27]
__global__ void prep_woW(const float* __restrict__ Wo, unsigned short* __restrict__ woW) {
    int idx = blockIdx.x * 256 + threadIdx.x;
    if (idx >= HID * KP) return;
    int n = idx / KP, k = idx - n * KP;
    float v = 0.f;
    if (k < AF) v = Wo[n * (AF + HID) + k];
    else if (k >= MOFF) v = Wo[n * (AF + HID) + (k - 27)];
    woW[idx] = f2bf(v);
}

// MFMA bf16 GEMM, out[M,512], 128x128 tile, 4 waves, K-step 32.
// Ring-of-3 LDS buffers, prefetch depth 2, counted vmcnt + raw s_barrier
// (one barrier per K-step, never drains the in-flight prefetch).
// LDS tiles [128][32] linear with chunk XOR swizzle phys = log ^ ((r^(r>>2))&3)
// applied on DMA source addr and frag read (both-sides rule).
template<int MODE>
__global__ __launch_bounds__(256) void gemm_mfma(
    const float* __restrict__ Afeat,
    const unsigned short* __restrict__ Amsg,
    const unsigned short* __restrict__ BW,
    const float* __restrict__ bias,
    unsigned short* __restrict__ outB,
    float* __restrict__ outF,
    int M)
{
    constexpr int FEAT  = (MODE == 2) ? AF : BF;
    constexpr int NK    = (MODE == 0) ? 5 : 21;
    constexpr int NFEAT = 5;    // tiles < NFEAT are feature tiles (reg-staged A)

    __shared__ unsigned short As[3][128 * 32];   // 3 x 8KB
    __shared__ unsigned short Bs[3][128 * 32];   // 3 x 8KB  -> 48KB total

    // bijective chunked XCD swizzle
    int nwg = gridDim.x;
    int q = nwg >> 3, r = nwg & 7;
    int xcd = blockIdx.x & 7, pos = blockIdx.x >> 3;
    int newid = (xcd < r ? xcd * (q + 1) : r * (q + 1) + (xcd - r) * q) + pos;
    const int m0 = (newid >> 2) * 128;
    const int n0 = (newid & 3) * 128;

    const int tid  = threadIdx.x;
    const int lane = tid & 63;
    const int wid  = tid >> 6;       // 4 waves, 2x2 -> 64x64 each
    const int wm   = wid >> 1;
    const int wn   = wid & 1;
    const int l15  = lane & 15;
    const int lg   = lane >> 4;

    const int drow = lane >> 2;      // DMA: row within 16-row group
    const int dchk = lane & 3;       // DMA: physical 16B chunk
    const int slr   = tid >> 1;      // slow path: row
    const int shalf = tid & 1;       // slow path: chunk pair

    auto stageB = [&](int ks, int buf) {   // 2 vmcnt loads / wave
#pragma unroll
        for (int j = 0; j < 2; j++) {
            int R0 = wid * 32 + j * 16;
            int lr = R0 + drow;
            int sw = (lr ^ (lr >> 2)) & 3;
            const unsigned short* src =
                BW + (size_t)(n0 + lr) * KP + ks * 32 + ((dchk ^ sw) << 3);
            dma16(src, &Bs[buf][R0 * 32]);
        }
    };
    auto stageA_dma = [&](int ks, int buf) {   // 2 vmcnt loads / wave
        const int kb = ks * 32 - MOFF;
#pragma unroll
        for (int j = 0; j < 2; j++) {
            int R0 = wid * 32 + j * 16;
            int lr = R0 + drow;
            int gr = m0 + lr; gr = gr < M ? gr : M - 1;   // clamp: masked at C-write
            int sw = (lr ^ (lr >> 2)) & 3;
            const unsigned short* src =
                Amsg + (size_t)gr * HID + kb + ((dchk ^ sw) << 3);
            dma16(src, &As[buf][R0 * 32]);
        }
    };
    auto stageA_slow = [&](int ks, int buf) {  // reg-staged, lgkm ds_write
        const int k0 = ks * 32;
        const int gr = m0 + slr;
        const int sw = (slr ^ (slr >> 2)) & 3;
#pragma unroll
        for (int h = 0; h < 2; h++) {
            int c = shalf * 2 + h;
            us8 v = {0, 0, 0, 0, 0, 0, 0, 0};
            if (gr < M) {
#pragma unroll
                for (int e = 0; e < 8; e++) {
                    int k = k0 + c * 8 + e;
                    if (k < FEAT) v[e] = f2bf(Afeat[(size_t)gr * FEAT + k]);
                }
            }
            *(us8*)&As[buf][slr * 32 + ((c ^ sw) << 3)] = v;
        }
    };

    const f4 fzero = {0.f, 0.f, 0.f, 0.f};
    f4 acc[4][4];
#pragma unroll
    for (int i = 0; i < 4; i++)
#pragma unroll
        for (int j = 0; j < 4; j++) acc[i][j] = fzero;

    // prologue: tiles 0,1 (feature tiles for every MODE); full drain once
    stageB(0, 0); stageA_slow(0, 0);
    if (NK > 1) { stageB(1, 1); stageA_slow(1, 1); }
    __syncthreads();    // full fence: buf0/buf1 ready, vmcnt drained

#pragma unroll
    for (int ks = 0; ks < NK; ks++) {
        const int cur = ks % 3;
        const int nx2 = ks + 2;
        // issue prefetch for tile ks+2 into the buffer freed by step ks-1
        if (nx2 < NK) {
            const int pb = nx2 % 3;
            stageB(nx2, pb);
            if (nx2 >= NFEAT) stageA_dma(nx2, pb);
            else              stageA_slow(nx2, pb);
        }
        // compute tile ks
        bfrag a[4], b[4];
#pragma unroll
        for (int mf = 0; mf < 4; mf++) {
            int rr = wm * 64 + mf * 16 + l15;
            int p = lg ^ ((rr ^ (rr >> 2)) & 3);
            a[mf] = *(const bfrag*)&As[cur][rr * 32 + p * 8];
        }
#pragma unroll
        for (int nf = 0; nf < 4; nf++) {
            int rr = wn * 64 + nf * 16 + l15;
            int p = lg ^ ((rr ^ (rr >> 2)) & 3);
            b[nf] = *(const bfrag*)&Bs[cur][rr * 32 + p * 8];
        }
#pragma unroll
        for (int mf = 0; mf < 4; mf++)
#pragma unroll
            for (int nf = 0; nf < 4; nf++)
                acc[mf][nf] = __builtin_amdgcn_mfma_f32_16x16x32_bf16(
                    a[mf], b[nf], acc[mf][nf], 0, 0, 0);
        // step boundary: ensure stage(ks+1) landed; leave stage(ks+2) in flight
        if (ks < NK - 1) {
            if (nx2 < NK) {
                if (nx2 >= NFEAT) WAITVM(4);   // stage(ks+2) fast: 4 loads fly
                else              WAITVM(2);   // stage(ks+2) slow: 2 B-loads fly
            } else {
                WAITVM(0);                     // nothing else in flight
            }
            __builtin_amdgcn_s_barrier();
            __builtin_amdgcn_sched_barrier(0);
        }
    }

    // epilogue: C/D layout col = lane&15, row = (lane>>4)*4 + reg  (validated r8)
#pragma unroll
    for (int mf = 0; mf < 4; mf++) {
#pragma unroll
        for (int rg = 0; rg < 4; rg++) {
            int R = m0 + wm * 64 + mf * 16 + lg * 4 + rg;
            if (R >= M) continue;
#pragma unroll
            for (int nf = 0; nf < 4; nf++) {
                int C = n0 + wn * 64 + nf * 16 + l15;
                float v = acc[mf][nf][rg];
                if (MODE == 2) {
                    v += bias[C];
                    outF[(size_t)R * HID + C] = fmaxf(v, 0.f);
                } else {
                    outB[(size_t)R * HID + C] = f2bf(fmaxf(v, 0.f));
                }
            }
        }
    }
}

// dm[b][:] = amsg[b2a[b]][:] - msg[b2revb[b]][:]   (bf16, fp32 subtract)
__global__ void dm_k(const unsigned short* __restrict__ amsg,
                     const unsigned short* __restrict__ msg,
                     const int* __restrict__ b2a, const int* __restrict__ b2revb,
                     unsigned short* __restrict__ dm) {
    int t = blockIdx.x * 256 + threadIdx.x;   // NBND*64
    if (t >= NBND * 64) return;
    int b = t >> 6, c8 = (t & 63) * 8;
    int ia = b2a[b], ir = b2revb[b];
    us8 x = *(const us8*)(amsg + (size_t)ia * HID + c8);
    us8 y = *(const us8*)(msg + (size_t)ir * HID + c8);
    us8 o;
#pragma unroll
    for (int j = 0; j < 8; j++) o[j] = f2bf(bf2f(x[j]) - bf2f(y[j]));
    *(us8*)(dm + (size_t)b * HID + c8) = o;
}

// amsg[a][:] = sum_nb msg[a2b[a][nb]][:]  (bf16, fp32 accumulate)
__global__ void gather_sum_k(const unsigned short* __restrict__ msg,
                             const int* __restrict__ a2b,
                             unsigned short* __restrict__ amsg) {
    int t = blockIdx.x * 256 + threadIdx.x;   // NAT*64
    if (t >= NAT * 64) return;
    int a = t >> 6, c8 = (t & 63) * 8;
    float s[8];
#pragma unroll
    for (int j = 0; j < 8; j++) s[j] = 0.f;
#pragma unroll
    for (int nb = 0; nb < MAXNB; nb++) {
        int b = a2b[a * MAXNB + nb];
        us8 v = *(const us8*)(msg + (size_t)b * HID + c8);
#pragma unroll
        for (int j = 0; j < 8; j++) s[j] += bf2f(v[j]);
    }
    us8 o;
#pragma unroll
    for (int j = 0; j < 8; j++) o[j] = f2bf(s[j]);
    *(us8*)(amsg + (size_t)a * HID + c8) = o;
}

// per-molecule mean pool; mol_ids sorted ascending; ah fp32
__global__ void pool_k(const float* __restrict__ ah, const int* __restrict__ mol_ids,
                       float* __restrict__ out) {
    int m = blockIdx.x;
    int c = blockIdx.y * 256 + threadIdx.x;
    int lo = 0, hi = NAT;
    while (lo < hi) { int mid = (lo + hi) >> 1; if (mol_ids[mid] < m) lo = mid + 1; else hi = mid; }
    int start = lo;
    hi = NAT;
    while (lo < hi) { int mid = (lo + hi) >> 1; if (mol_ids[mid] < m + 1) lo = mid + 1; else hi = mid; }
    int end = lo;
    float s = 0.f;
    for (int a = start; a < end; a++) s += ah[(size_t)a * HID + c];
    float cnt = (float)(end - start);
    out[(size_t)m * HID + c] = s / fmaxf(cnt, 1.f);
}

extern "C" void kernel_launch(void* const* d_in, const int* in_sizes, int n_in,
                              void* d_out, int out_size, void* d_ws, size_t ws_size,
                              hipStream_t stream) {
    const float* f_atoms     = (const float*)d_in[0];
    const float* f_bonds     = (const float*)d_in[1];
    const float* ano_f_atoms = (const float*)d_in[2];
    const float* ano_f_bonds = (const float*)d_in[3];
    const float* Wi = (const float*)d_in[4];
    const float* Wh = (const float*)d_in[5];
    const float* Wo = (const float*)d_in[6];
    const float* bo = (const float*)d_in[7];
    const int* a2b     = (const int*)d_in[8];
    const int* b2a     = (const int*)d_in[9];
    const int* b2revb  = (const int*)d_in[10];
    const int* mol_ids = (const int*)d_in[11];
    const int* ano_a2b     = (const int*)d_in[12];
    const int* ano_b2a     = (const int*)d_in[13];
    const int* ano_b2revb  = (const int*)d_in[14];
    const int* ano_mol_ids = (const int*)d_in[15];
    float* out = (float*)d_out;

    // workspace layout (bf16 messages): 257.4 MB total
    char* ws = (char*)d_ws;
    unsigned short* msgA = (unsigned short*)ws;  ws += (size_t)NBND * HID * 2;
    char* msgB_raw = ws;
    unsigned short* msgB = (unsigned short*)ws;  ws += (size_t)NBND * HID * 2;
    unsigned short* amsg = (unsigned short*)ws;  ws += (size_t)NAT * HID * 2;
    unsigned short* catW = (unsigned short*)ws;  ws += (size_t)HID * KP * 2;
    unsigned short* woW  = (unsigned short*)ws;  ws += (size_t)HID * KP * 2;

    const size_t need = ((size_t)2 * NBND + NAT) * HID * 2 + (size_t)2 * HID * KP * 2;
    if (ws_size < need) return;   // visible failure, no fault

    prep_catW<<<(HID * KP + 255) / 256, 256, 0, stream>>>(Wi, Wh, catW);
    prep_woW<<<(HID * KP + 255) / 256, 256, 0, stream>>>(Wo, woW);

    const int nwgB = 4 * ((NBND + 127) / 128);   // 3128
    const int nwgA = 4 * ((NAT + 127) / 128);    // 1564
    const int gsBlocks = (NAT * 64 + 255) / 256;
    const int dmBlocks = (NBND * 64 + 255) / 256;

    for (int e = 0; e < 2; e++) {
        const float* fa = e ? ano_f_atoms : f_atoms;
        const float* fb = e ? ano_f_bonds : f_bonds;
        const int* e_a2b = e ? ano_a2b : a2b;
        const int* e_b2a = e ? ano_b2a : b2a;
        const int* e_b2revb = e ? ano_b2revb : b2revb;
        const int* e_mids = e ? ano_mol_ids : mol_ids;

        // msgA = relu(f_bonds @ Wi^T)
        gemm_mfma<0><<<nwgB, 256, 0, stream>>>(fb, (const unsigned short*)nullptr, catW,
                                               nullptr, msgA, nullptr, NBND);
        for (int d = 0; d < 2; d++) {
            gather_sum_k<<<gsBlocks, 256, 0, stream>>>(msgA, e_a2b, amsg);
            dm_k<<<dmBlocks, 256, 0, stream>>>(amsg, msgA, e_b2a, e_b2revb, msgB);
            // msgA = relu(concat(f_bonds, dm) @ [Wi|0|Wh]^T)
            gemm_mfma<1><<<nwgB, 256, 0, stream>>>(fb, msgB, catW,
                                                   nullptr, msgA, nullptr, NBND);
        }
        gather_sum_k<<<gsBlocks, 256, 0, stream>>>(msgA, e_a2b, amsg);
        // ah(fp32, reuses msgB region) = relu(concat(f_atoms, amsg) @ Wo^T + bo)
        float* ah = (float*)msgB_raw;
        gemm_mfma<2><<<nwgA, 256, 0, stream>>>(fa, amsg, woW,
                                               bo, nullptr, ah, NAT);
        pool_k<<<dim3(NMOL, 2), 256, 0, stream>>>(ah, e_mids, out + (size_t)e * NMOL * HID);
    }
}